// Round 3
// baseline (564.927 us; speedup 1.0000x reference)
//
#include <hip/hip_runtime.h>
#include <hip/hip_bf16.h>
#include <math.h>

#define Bn 16
#define Cc 256
#define Oo 128
#define HWn 4096
#define Ntot 65536   // Bn*HWn

typedef __attribute__((ext_vector_type(8))) __bf16 bf16x8;
typedef __attribute__((ext_vector_type(4))) float f32x4;

__device__ __forceinline__ unsigned short f2bf(float f) {
    unsigned u = __builtin_bit_cast(unsigned, f);
    u = (u + 0x7FFFu + ((u >> 16) & 1u)) >> 16;
    return (unsigned short)u;
}
__device__ __forceinline__ float bf2f(unsigned short h) {
    unsigned u = ((unsigned)h) << 16;
    return __builtin_bit_cast(float, u);
}

// ---------------- w fp32 -> bf16 pre-pass (tiny) ----------------
__global__ void wprep(const float* __restrict__ wgw, const float* __restrict__ wxw,
                      unsigned short* __restrict__ wbg, unsigned short* __restrict__ wbx)
{
    const int i = blockIdx.x * 256 + threadIdx.x;   // 0..32767
    wbg[i] = f2bf(wgw[i]);
    wbx[i] = f2bf(wxw[i]);
}

// ---------------- fused conv1x1 (bf16 MFMA, no LDS, no barriers) ----------------
// z=0: tg = wg_w @ g + wg_b ; z=1: tx = wx_w @ x + wx_b.  Output bf16 [b][o][hw].
// Block: 128(o) x 128(hw) tile; each wave owns full o=128, hw slice of 32 (no
// duplicated input reads). A (w, bf16, L2-hot) loaded per-kg as dwordx4 frags;
// B (input fp32) loaded as 8 scalar dwords per frag, packed to bf16 in-reg.
__global__ __launch_bounds__(256, 3)
void conv_mfma(const float* __restrict__ gin, const float* __restrict__ xin,
               const unsigned short* __restrict__ wbg, const unsigned short* __restrict__ wbx,
               const float* __restrict__ wgb, const float* __restrict__ wxb,
               unsigned short* __restrict__ tg, unsigned short* __restrict__ tx,
               float* __restrict__ gsum, float* __restrict__ gsq,
               float* __restrict__ xsum, float* __restrict__ xsq)
{
    const int z = blockIdx.z;
    const float* in            = z ? xin : gin;
    const unsigned short* wb   = z ? wbx : wbg;
    const float* bias          = z ? wxb : wgb;
    unsigned short* outT       = z ? tx : tg;
    float* osum                = z ? xsum : gsum;
    float* osq                 = z ? xsq  : gsq;

    const int t    = threadIdx.x;
    const int b    = blockIdx.y;
    const int hw0  = blockIdx.x * 128;
    const int lane = t & 63;
    const int wv   = t >> 6;
    const int n0   = wv * 32;          // wave's hw slice
    const int q    = lane >> 4;
    const int r    = lane & 15;

    f32x4 acc[8][2];
#pragma unroll
    for (int i = 0; i < 8; i++)
#pragma unroll
        for (int j = 0; j < 2; j++) acc[i][j] = (f32x4){0.f, 0.f, 0.f, 0.f};

    // base for B loads: in[b][c][hw0 + n0 + r + ...]
    const float* ibase = in + (((size_t)b * Cc) << 12) + hw0 + n0 + r;

    for (int kg = 0; kg < 8; kg++) {
        const int c0 = kg * 32 + q * 8;          // this lane's k-group start
        // A fragments: w[mi*16 + r][c0 .. c0+7] as bf16x8 (one dwordx4, L2-hot)
        bf16x8 af[8];
#pragma unroll
        for (int mi = 0; mi < 8; mi++)
            af[mi] = *(const bf16x8*)(wb + (mi * 16 + r) * Cc + c0);

#pragma unroll
        for (int ni = 0; ni < 2; ni++) {
            const float* p = ibase + (((size_t)c0) << 12) + ni * 16;
            float bv[8];
#pragma unroll
            for (int j = 0; j < 8; j++) bv[j] = p[(size_t)j << 12];
            unsigned short bs[8];
#pragma unroll
            for (int j = 0; j < 8; j++) bs[j] = f2bf(bv[j]);
            const bf16x8 bfr = *(const bf16x8*)bs;
#pragma unroll
            for (int mi = 0; mi < 8; mi++)
                acc[mi][ni] = __builtin_amdgcn_mfma_f32_16x16x32_bf16(af[mi], bfr, acc[mi][ni], 0, 0, 0);
        }
    }

    // epilogue: bias, bf16 store, per-o stats (fp32)
#pragma unroll
    for (int mi = 0; mi < 8; mi++) {
#pragma unroll
        for (int reg = 0; reg < 4; reg++) {
            const int o = mi * 16 + q * 4 + reg;
            const float bo = bias[o];
            float s1 = 0.f, s2 = 0.f;
#pragma unroll
            for (int ni = 0; ni < 2; ni++) {
                const float v = acc[mi][ni][reg] + bo;
                outT[(((size_t)b * Oo + o) << 12) + hw0 + n0 + ni * 16 + r] = f2bf(v);
                s1 += v; s2 += v * v;
            }
#pragma unroll
            for (int d = 1; d < 16; d <<= 1) {
                s1 += __shfl_xor(s1, d);
                s2 += __shfl_xor(s2, d);
            }
            if (r == 0) { atomicAdd(&osum[o], s1); atomicAdd(&osq[o], s2); }
        }
    }
}

// ---------------- finalize BN stats for both convs ----------------
__global__ void finalize1(const float* __restrict__ gsum, const float* __restrict__ gsq,
                          const float* __restrict__ xsum, const float* __restrict__ xsq,
                          const float* __restrict__ wg_gamma, const float* __restrict__ wg_beta,
                          const float* __restrict__ wx_gamma, const float* __restrict__ wx_beta,
                          const float* __restrict__ psi_w, float4* __restrict__ coef)
{
    const int o = threadIdx.x;
    const float invN = 1.f / (float)Ntot;
    float mg = gsum[o] * invN;
    float vg = gsq[o] * invN - mg * mg;
    float gs = wg_gamma[o] * rsqrtf(vg + 1e-5f);
    float gh = wg_beta[o] - mg * gs;
    float mx = xsum[o] * invN;
    float vx = xsq[o] * invN - mx * mx;
    float xs = wx_gamma[o] * rsqrtf(vx + 1e-5f);
    float xh = wx_beta[o] - mx * xs;
    coef[o] = make_float4(gs, xs, gh + xh, psi_w[o]);
}

// ---------------- psi partial: atomic-add 32-o partial into S (bf16 reads) ----------------
__global__ __launch_bounds__(256)
void psi_partial(const unsigned short* __restrict__ tg, const unsigned short* __restrict__ tx,
                 const float4* __restrict__ coef, float* __restrict__ S)
{
    const int p  = blockIdx.x * 256 + threadIdx.x;
    const int b  = p >> 12;
    const int hw = p & 4095;
    const int og = blockIdx.y * 32;
    const unsigned short* g0 = tg + (((size_t)b * Oo) << 12) + hw;
    const unsigned short* x0 = tx + (((size_t)b * Oo) << 12) + hw;
    float s = 0.f;
#pragma unroll
    for (int oi = 0; oi < 32; oi++) {
        const int o = og + oi;
        const float4 cf = coef[o];
        const float gv = bf2f(g0[(size_t)o << 12]);
        const float xv = bf2f(x0[(size_t)o << 12]);
        s += cf.w * fmaxf(cf.x * gv + cf.y * xv + cf.z, 0.f);
    }
    atomicAdd(&S[p], s);
}

// ---------------- psi combine: add bias, global stats of s ----------------
__global__ __launch_bounds__(256)
void psi_combine(float* __restrict__ S, const float* __restrict__ pb, float* __restrict__ psum)
{
    const int p = blockIdx.x * 256 + threadIdx.x;
    const float s = pb[0] + S[p];
    S[p] = s;
    float s1 = s, s2 = s * s;
#pragma unroll
    for (int d = 1; d < 64; d <<= 1) {
        s1 += __shfl_xor(s1, d);
        s2 += __shfl_xor(s2, d);
    }
    __shared__ float r1[4], r2[4];
    const int wid = threadIdx.x >> 6, lid = threadIdx.x & 63;
    if (lid == 0) { r1[wid] = s1; r2[wid] = s2; }
    __syncthreads();
    if (threadIdx.x == 0) {
        atomicAdd(&psum[0], r1[0] + r1[1] + r1[2] + r1[3]);
        atomicAdd(&psum[1], r2[0] + r2[1] + r2[2] + r2[3]);
    }
}

__global__ void finalize2(const float* __restrict__ psum, const float* __restrict__ psi_gamma,
                          const float* __restrict__ psi_beta, float* __restrict__ pc)
{
    const float invN = 1.f / (float)Ntot;
    const float m = psum[0] * invN;
    const float v = psum[1] * invN - m * m;
    const float ps = psi_gamma[0] * rsqrtf(v + 1e-5f);
    pc[0] = ps;
    pc[1] = psi_beta[0] - m * ps;
}

// ---------------- out = x * sigmoid(pscale*s + pshift) ----------------
__global__ __launch_bounds__(256)
void final_mul_kernel(const float* __restrict__ x, const float* __restrict__ S,
                      const float* __restrict__ pc, float* __restrict__ out)
{
    const size_t i = ((size_t)blockIdx.x * 256 + threadIdx.x) * 4;
    const int hw = (int)(i & 4095);
    const size_t bc = i >> 12;
    const int b = (int)(bc >> 8);
    const float ps = pc[0], psh = pc[1];
    const float4 xv = *(const float4*)(x + i);
    const float4 sv = *(const float4*)(S + ((size_t)b << 12) + hw);
    float4 r;
    r.x = xv.x * (1.f / (1.f + __expf(-(ps * sv.x + psh))));
    r.y = xv.y * (1.f / (1.f + __expf(-(ps * sv.y + psh))));
    r.z = xv.z * (1.f / (1.f + __expf(-(ps * sv.z + psh))));
    r.w = xv.w * (1.f / (1.f + __expf(-(ps * sv.w + psh))));
    *(float4*)(out + i) = r;
}

extern "C" void kernel_launch(void* const* d_in, const int* in_sizes, int n_in,
                              void* d_out, int out_size, void* d_ws, size_t ws_size,
                              hipStream_t stream)
{
    const float* g         = (const float*)d_in[0];
    const float* x         = (const float*)d_in[1];
    const float* wg_w      = (const float*)d_in[2];
    const float* wg_b      = (const float*)d_in[3];
    const float* wg_gamma  = (const float*)d_in[4];
    const float* wg_beta   = (const float*)d_in[5];
    const float* wx_w      = (const float*)d_in[6];
    const float* wx_b      = (const float*)d_in[7];
    const float* wx_gamma  = (const float*)d_in[8];
    const float* wx_beta   = (const float*)d_in[9];
    const float* psi_w     = (const float*)d_in[10];
    const float* psi_b     = (const float*)d_in[11];
    const float* psi_gamma = (const float*)d_in[12];
    const float* psi_beta  = (const float*)d_in[13];

    float* out = (float*)d_out;
    // d_out doubles as scratch: bf16 tg/tx in first 32 MB, bf16 weights at
    // +48 MB; everything overwritten by final_mul_kernel afterwards.
    unsigned short* tg = (unsigned short*)out;                       // 8388608 bf16
    unsigned short* tx = tg + (size_t)Bn * Oo * HWn;                 // 8388608 bf16
    unsigned short* wbg = (unsigned short*)(out + 12 * 1024 * 1024); // 32768 bf16
    unsigned short* wbx = wbg + Oo * Cc;                             // 32768 bf16

    float* ws   = (float*)d_ws;
    float* S    = ws;                 // 65536 floats (accumulated via atomics)
    float* gsum = ws + 65536;         // 128
    float* gsq  = ws + 65664;         // 128
    float* xsum = ws + 65792;         // 128
    float* xsq  = ws + 65920;         // 128
    float* psum = ws + 66048;         // 2 (+2 pad)
    float4* coef = (float4*)(ws + 66052);  // 128 float4 (16B aligned)
    float* pc   = ws + 66564;         // 2

    // zero S + all stat accumulators
    hipMemsetAsync(ws, 0, 66052 * sizeof(float), stream);

    wprep<<<Oo * Cc / 256, 256, 0, stream>>>(wg_w, wx_w, wbg, wbx);
    conv_mfma<<<dim3(HWn / 128, Bn, 2), 256, 0, stream>>>(
        g, x, wbg, wbx, wg_b, wx_b, tg, tx, gsum, gsq, xsum, xsq);
    finalize1<<<1, 128, 0, stream>>>(gsum, gsq, xsum, xsq, wg_gamma, wg_beta,
                                     wx_gamma, wx_beta, psi_w, coef);
    psi_partial<<<dim3(Ntot / 256, 4), 256, 0, stream>>>(tg, tx, coef, S);
    psi_combine<<<Ntot / 256, 256, 0, stream>>>(S, psi_b, psum);
    finalize2<<<1, 1, 0, stream>>>(psum, psi_gamma, psi_beta, pc);
    final_mul_kernel<<<(Ntot * Cc) / (4 * 256), 256, 0, stream>>>(x, S, pc, out);
}